// Round 4
// baseline (153.025 us; speedup 1.0000x reference)
//
#include <hip/hip_runtime.h>
#include <hip/hip_bf16.h>

#define NROWS 4096
#define DMODEL 512
#define NHEAD 8
#define DKH 64
#define ND (NROWS * DMODEL)   // 2097152
#define DD (DMODEL * DMODEL)  // 262144

typedef unsigned short u16;
typedef __attribute__((ext_vector_type(8))) short short8;
typedef __attribute__((ext_vector_type(4))) float floatx4;

// ---------- helpers ----------
__device__ __forceinline__ u16 f2b(float f) {
    unsigned u = __float_as_uint(f);
    unsigned r = (u + 0x7fffu + ((u >> 16) & 1u)) >> 16;
    return (u16)r;
}
__device__ __forceinline__ float b2f(u16 v) {
    return __uint_as_float(((unsigned)v) << 16);
}
__device__ __forceinline__ void async16(const void* g, void* l) {
    // global -> LDS direct, 16B/lane; LDS dest = wave-uniform base + lane*16
    __builtin_amdgcn_global_load_lds(g, l, 16, 0, 0);
}
__device__ __forceinline__ short8 cvt8(float4 a0, float4 a1) {
    short8 av;
    av[0] = f2b(a0.x); av[1] = f2b(a0.y); av[2] = f2b(a0.z); av[3] = f2b(a0.w);
    av[4] = f2b(a1.x); av[5] = f2b(a1.y); av[6] = f2b(a1.z); av[7] = f2b(a1.w);
    return av;
}

// ---------- 1. W (K x N) -> Wt (N x K) bf16 ----------
__global__ __launch_bounds__(256) void convert_w(
    const float* __restrict__ W0, const float* __restrict__ W1,
    const float* __restrict__ W2, const float* __restrict__ W3,
    u16* __restrict__ T0, u16* __restrict__ T1, u16* __restrict__ T2,
    u16* __restrict__ T3) {
    __shared__ float tile[32][33];
    int z = blockIdx.z;
    const float* W = z == 0 ? W0 : (z == 1 ? W1 : (z == 2 ? W2 : W3));
    u16* T = z == 0 ? T0 : (z == 1 ? T1 : (z == 2 ? T2 : T3));
    int n0 = blockIdx.x * 32, k0 = blockIdx.y * 32;
    int tx = threadIdx.x, ty = threadIdx.y;  // (32, 8)
#pragma unroll
    for (int r = 0; r < 32; r += 8)
        tile[ty + r][tx] = W[(size_t)(k0 + ty + r) * DMODEL + n0 + tx];
    __syncthreads();
#pragma unroll
    for (int r = 0; r < 32; r += 8) {
        int n = n0 + ty + r, k = k0 + tx;
        T[(size_t)n * DMODEL + k] = f2b(tile[tx][ty + r]);
    }
}

// ---------- 2. fused convert + Q/K/V projection + rank-1 attention ----------
// Block = one (M-panel of 64 rows, one head of 64 cols). 512 blocks, 2/CU.
// Computes Q,K,V [64x64] tiles via 3 parallel GEMMs (acc[3][2][2]), stages
// them (+bias) in LDS, runs softmax attention in-block, writes T = x_q - att.
__global__ __launch_bounds__(256, 2) void proj_attn(
    const float* __restrict__ xq, const float* __restrict__ xk,
    const float* __restrict__ xv, const u16* __restrict__ wtq,
    const u16* __restrict__ wtk, const u16* __restrict__ wtv,
    const float* __restrict__ bq, const float* __restrict__ bk,
    const float* __restrict__ bv, u16* __restrict__ Tb) {
    // smem: staging = lA[2][3][2048] (0..12287) + lB[2][3][2048] (12288..24575)
    // attn overlay (after K-loop): q/k/v [3][64*68] at 0 / 4352 / 8704
    __shared__ __align__(16) u16 smem[24576];

    const int d = blockIdx.x;
    const int id = (d & 7) * 64 + (d >> 3);  // XCD-chunked: 64 tiles per XCD
    const int tileM = (id >> 3) * 64;
    const int tileN = (id & 7) * 64;  // == head * 64

    const float* XA[3] = {xq, xk, xv};
    const u16* WT[3] = {wtq, wtk, wtv};
    const float* BIAS[3] = {bq, bk, bv};

    const int tid = threadIdx.x;
    const int wave = tid >> 6, lane = tid & 63;
    const int wm = wave >> 1, wn = wave & 1;
    const int lr4 = lane >> 2, ls = lane & 3;
    const int lrow = lane & 15, sk = lane >> 4;

    // A reg-staging: thread -> (row = tid>>2, 8-elem slot = tid&3), x3 mats
    const int arow = tid >> 2, aslot = tid & 3;
    const int asw = aslot ^ ((arow >> 1) & 3);
    const float* aptr[3];
#pragma unroll
    for (int m = 0; m < 3; m++)
        aptr[m] = XA[m] + (size_t)(tileM + arow) * 512 + aslot * 8;

    floatx4 acc[3][2][2];
#pragma unroll
    for (int m = 0; m < 3; m++)
#pragma unroll
        for (int i = 0; i < 2; i++)
#pragma unroll
            for (int j = 0; j < 2; j++)
                acc[m][i][j] = (floatx4){0.f, 0.f, 0.f, 0.f};

    // ---- prologue: stage K-tile 0 into buffer 0
#pragma unroll
    for (int i = 0; i < 3; i++) {
        int c = wave * 3 + i, m = c >> 2, ch = c & 3;
        int r = ch * 16 + lr4, s = ls ^ ((r >> 1) & 3);
        async16(WT[m] + (size_t)(tileN + r) * 512 + s * 8,
                &smem[12288 + m * 2048 + ch * 512]);
    }
#pragma unroll
    for (int m = 0; m < 3; m++) {
        float4 a0 = *(const float4*)aptr[m];
        float4 a1 = *(const float4*)(aptr[m] + 4);
        *(short8*)&smem[m * 2048 + arow * 32 + asw * 8] = cvt8(a0, a1);
    }
    __syncthreads();

    for (int t = 0; t < 16; ++t) {
        const int cur = t & 1, nxt = cur ^ 1;
        float4 na[3][2];
        if (t < 15) {
            // issue next-tile loads first: A to regs, B direct to alt buffer
#pragma unroll
            for (int m = 0; m < 3; m++) {
                const float* p = aptr[m] + (t + 1) * 32;
                na[m][0] = *(const float4*)p;
                na[m][1] = *(const float4*)(p + 4);
            }
#pragma unroll
            for (int i = 0; i < 3; i++) {
                int c = wave * 3 + i, m = c >> 2, ch = c & 3;
                int r = ch * 16 + lr4, s = ls ^ ((r >> 1) & 3);
                async16(WT[m] + (size_t)(tileN + r) * 512 + (t + 1) * 32 + s * 8,
                        &smem[12288 + (nxt * 3 + m) * 2048 + ch * 512]);
            }
        }
        // compute current tile
#pragma unroll
        for (int m = 0; m < 3; m++) {
            short8 afr[2], bfr[2];
#pragma unroll
            for (int mi = 0; mi < 2; ++mi) {
                int r = wm * 32 + mi * 16 + lrow;
                int s = sk ^ ((r >> 1) & 3);
                afr[mi] = *(const short8*)&smem[(cur * 3 + m) * 2048 + r * 32 + s * 8];
            }
#pragma unroll
            for (int ni = 0; ni < 2; ++ni) {
                int r = wn * 32 + ni * 16 + lrow;
                int s = sk ^ ((r >> 1) & 3);
                bfr[ni] = *(const short8*)&smem[12288 + (cur * 3 + m) * 2048 + r * 32 + s * 8];
            }
#pragma unroll
            for (int mi = 0; mi < 2; ++mi)
#pragma unroll
                for (int ni = 0; ni < 2; ++ni)
                    acc[m][mi][ni] = __builtin_amdgcn_mfma_f32_16x16x32_bf16(
                        afr[mi], bfr[ni], acc[m][mi][ni], 0, 0, 0);
        }
        if (t < 15) {
#pragma unroll
            for (int m = 0; m < 3; m++)
                *(short8*)&smem[(nxt * 3 + m) * 2048 + arow * 32 + asw * 8] =
                    cvt8(na[m][0], na[m][1]);
        }
        __syncthreads();
    }

    // ---- write Q,K,V (+bias) into attn overlay; stride 68 breaks conflicts
#pragma unroll
    for (int m = 0; m < 3; m++) {
#pragma unroll
        for (int mi = 0; mi < 2; ++mi)
#pragma unroll
            for (int ni = 0; ni < 2; ++ni) {
                int col = wn * 32 + ni * 16 + lrow;
                float bv_ = BIAS[m][tileN + col];
#pragma unroll
                for (int r2 = 0; r2 < 4; r2++) {
                    int row = wm * 32 + mi * 16 + sk * 4 + r2;
                    smem[m * 4352 + row * 68 + col] =
                        f2b(acc[m][mi][ni][r2] + bv_);
                }
            }
    }
    __syncthreads();

    // ---- rank-1 channel attention: lane = output channel, broadcast over j
    const u16* lq = smem;
    const u16* lk = smem + 4352;
    const u16* lv = smem + 8704;
    for (int i = 0; i < 16; ++i) {
        int nl = wave * 16 + i;  // local row
        float qs = b2f(lq[nl * 68 + lane]) * 0.125f;  // 1/sqrt(64)
        float num = 0.f, den = 0.f;
#pragma unroll
        for (int j = 0; j < 64; ++j) {
            float kj = b2f(lk[nl * 68 + j]);  // wave-uniform -> broadcast
            float vj = b2f(lv[nl * 68 + j]);
            float e = __expf(qs * kj);
            den += e;
            num += e * vj;
        }
        size_t gi = (size_t)(tileM + nl) * 512 + tileN + lane;
        Tb[gi] = f2b(xq[gi] - num / den);
    }
}

// ---------- 3. output GEMM: C = T[M,K] @ Wto[N,K]^T + bo (fp32 out) ----------
// BM=64, BN=64, 512 blocks (2/CU), 2-phase double buffer.
__global__ __launch_bounds__(256, 2) void out_gemm(const u16* __restrict__ T,
                                                   const u16* __restrict__ wto,
                                                   const float* __restrict__ bo,
                                                   float* __restrict__ C) {
    __shared__ __align__(16) u16 sA[2][2048];
    __shared__ __align__(16) u16 sB[2][2048];
    const int d = blockIdx.x;
    const int id = (d & 7) * 64 + (d >> 3);
    const int tileM = (id >> 3) * 64;
    const int tileN = (id & 7) * 64;

    const int tid = threadIdx.x;
    const int wave = tid >> 6, lane = tid & 63;
    const int wm = wave >> 1, wn = wave & 1;
    const int lr4 = lane >> 2, ls = lane & 3;
    const int lrow = lane & 15, sk = lane >> 4;

    // staging: wave handles A chunk[wave] and B chunk[wave] (16 rows each)
    const int r0 = wave * 16 + lr4;
    const int s0 = ls ^ ((r0 >> 1) & 3);
    const u16* aptr = T + (size_t)(tileM + r0) * 512 + s0 * 8;
    const u16* bptr = wto + (size_t)(tileN + r0) * 512 + s0 * 8;

    floatx4 acc[2][2];
#pragma unroll
    for (int i = 0; i < 2; i++)
#pragma unroll
        for (int j = 0; j < 2; j++) acc[i][j] = (floatx4){0.f, 0.f, 0.f, 0.f};

    async16(aptr, &sA[0][wave * 512]);
    async16(bptr, &sB[0][wave * 512]);
    __syncthreads();

    for (int t = 0; t < 16; ++t) {
        const int cur = t & 1, nxt = cur ^ 1;
        if (t < 15) {
            async16(aptr + (t + 1) * 32, &sA[nxt][wave * 512]);
            async16(bptr + (t + 1) * 32, &sB[nxt][wave * 512]);
        }
        short8 afr[2], bfr[2];
#pragma unroll
        for (int mi = 0; mi < 2; ++mi) {
            int r = wm * 32 + mi * 16 + lrow;
            int s = sk ^ ((r >> 1) & 3);
            afr[mi] = *(const short8*)&sA[cur][r * 32 + s * 8];
        }
#pragma unroll
        for (int ni = 0; ni < 2; ++ni) {
            int r = wn * 32 + ni * 16 + lrow;
            int s = sk ^ ((r >> 1) & 3);
            bfr[ni] = *(const short8*)&sB[cur][r * 32 + s * 8];
        }
#pragma unroll
        for (int mi = 0; mi < 2; ++mi)
#pragma unroll
            for (int ni = 0; ni < 2; ++ni)
                acc[mi][ni] = __builtin_amdgcn_mfma_f32_16x16x32_bf16(
                    afr[mi], bfr[ni], acc[mi][ni], 0, 0, 0);
        __syncthreads();
    }

#pragma unroll
    for (int mi = 0; mi < 2; ++mi)
#pragma unroll
        for (int ni = 0; ni < 2; ++ni) {
            int col = tileN + wn * 32 + ni * 16 + lrow;
            float bv = bo[col];
#pragma unroll
            for (int r2 = 0; r2 < 4; r2++) {
                int row = tileM + wm * 32 + mi * 16 + sk * 4 + r2;
                C[(size_t)row * 512 + col] = acc[mi][ni][r2] + bv;
            }
        }
}

// ---------- launch ----------
extern "C" void kernel_launch(void* const* d_in, const int* in_sizes, int n_in,
                              void* d_out, int out_size, void* d_ws,
                              size_t ws_size, hipStream_t stream) {
    const float* x_q = (const float*)d_in[0];
    const float* x_k = (const float*)d_in[1];
    const float* x_v = (const float*)d_in[2];
    const float* Wq = (const float*)d_in[3];
    const float* bq = (const float*)d_in[4];
    const float* Wk = (const float*)d_in[5];
    const float* bk = (const float*)d_in[6];
    const float* Wv = (const float*)d_in[7];
    const float* bv = (const float*)d_in[8];
    const float* Wo = (const float*)d_in[9];
    const float* bo = (const float*)d_in[10];

    u16* ws = (u16*)d_ws;
    u16* wtq = ws;
    u16* wtk = wtq + DD;
    u16* wtv = wtk + DD;
    u16* wto = wtv + DD;
    u16* Tb = wto + DD;

    convert_w<<<dim3(16, 16, 4), dim3(32, 8), 0, stream>>>(Wq, Wk, Wv, Wo, wtq,
                                                           wtk, wtv, wto);
    proj_attn<<<dim3(512), 256, 0, stream>>>(x_q, x_k, x_v, wtq, wtk, wtv, bq,
                                             bk, bv, Tb);
    out_gemm<<<dim3(512), 256, 0, stream>>>(Tb, wto, bo, (float*)d_out);
}

// Round 5
// 146.388 us; speedup vs baseline: 1.0453x; 1.0453x over previous
//
#include <hip/hip_runtime.h>
#include <hip/hip_bf16.h>

#define NROWS 4096
#define DMODEL 512
#define NHEAD 8
#define DKH 64
#define ND (NROWS * DMODEL)   // 2097152
#define DD (DMODEL * DMODEL)  // 262144

typedef unsigned short u16;
typedef __attribute__((ext_vector_type(8))) short short8;
typedef __attribute__((ext_vector_type(4))) float floatx4;

// ---------- helpers ----------
__device__ __forceinline__ u16 f2b(float f) {
    unsigned u = __float_as_uint(f);
    unsigned r = (u + 0x7fffu + ((u >> 16) & 1u)) >> 16;
    return (u16)r;
}
__device__ __forceinline__ float b2f(u16 v) {
    return __uint_as_float(((unsigned)v) << 16);
}
__device__ __forceinline__ void async16(const void* g, void* l) {
    // global -> LDS direct, 16B/lane; LDS dest = wave-uniform base + lane*16
    __builtin_amdgcn_global_load_lds(g, l, 16, 0, 0);
}
__device__ __forceinline__ short8 cvt8(float4 a0, float4 a1) {
    short8 av;
    av[0] = f2b(a0.x); av[1] = f2b(a0.y); av[2] = f2b(a0.z); av[3] = f2b(a0.w);
    av[4] = f2b(a1.x); av[5] = f2b(a1.y); av[6] = f2b(a1.z); av[7] = f2b(a1.w);
    return av;
}

// ---------- 1. W (K x N) -> Wt (N x K) bf16 ----------
__global__ __launch_bounds__(256) void convert_w(
    const float* __restrict__ W0, const float* __restrict__ W1,
    const float* __restrict__ W2, const float* __restrict__ W3,
    u16* __restrict__ T0, u16* __restrict__ T1, u16* __restrict__ T2,
    u16* __restrict__ T3) {
    __shared__ float tile[32][33];
    int z = blockIdx.z;
    const float* W = z == 0 ? W0 : (z == 1 ? W1 : (z == 2 ? W2 : W3));
    u16* T = z == 0 ? T0 : (z == 1 ? T1 : (z == 2 ? T2 : T3));
    int n0 = blockIdx.x * 32, k0 = blockIdx.y * 32;
    int tx = threadIdx.x, ty = threadIdx.y;  // (32, 8)
#pragma unroll
    for (int r = 0; r < 32; r += 8)
        tile[ty + r][tx] = W[(size_t)(k0 + ty + r) * DMODEL + n0 + tx];
    __syncthreads();
#pragma unroll
    for (int r = 0; r < 32; r += 8) {
        int n = n0 + ty + r, k = k0 + tx;
        T[(size_t)n * DMODEL + k] = f2b(tile[tx][ty + r]);
    }
}

// ---------- 2. fused convert + Q/K/V projection + rank-1 attention ----------
// Block = one (M-panel of 64 rows, one head of 64 cols). 512 blocks, 2/CU.
// GEMM phase: acc[3][2][2], 2-phase dbuf staging (as R4, verified).
// Attention phase v2: overlay q as bf16, k (pre-scaled) and v as F32;
// inner loop = broadcast ds_read_b128 float4 + __expf (no per-element b2f).
__global__ __launch_bounds__(256, 2) void proj_attn(
    const float* __restrict__ xq, const float* __restrict__ xk,
    const float* __restrict__ xv, const u16* __restrict__ wtq,
    const u16* __restrict__ wtk, const u16* __restrict__ wtv,
    const float* __restrict__ bq, const float* __restrict__ bk,
    const float* __restrict__ bv, u16* __restrict__ Tb) {
    // staging: lA[2][3][2048] u16 (0..12287) + lB[2][3][2048] u16 (12288..24575)
    // overlay (after K-loop): q u16[64][68] @0; k f32[64][68] @byte 8704;
    //                         v f32[64][68] @byte 26112  (total 43520 B)
    __shared__ __align__(16) u16 smem[24576];

    const int d = blockIdx.x;
    const int id = (d & 7) * 64 + (d >> 3);  // XCD-chunked: 64 tiles per XCD
    const int tileM = (id >> 3) * 64;
    const int tileN = (id & 7) * 64;  // == head * 64

    const float* XA[3] = {xq, xk, xv};
    const u16* WT[3] = {wtq, wtk, wtv};

    const int tid = threadIdx.x;
    const int wave = tid >> 6, lane = tid & 63;
    const int wm = wave >> 1, wn = wave & 1;
    const int lr4 = lane >> 2, ls = lane & 3;
    const int lrow = lane & 15, sk = lane >> 4;

    // A reg-staging: thread -> (row = tid>>2, 8-elem slot = tid&3), x3 mats
    const int arow = tid >> 2, aslot = tid & 3;
    const int asw = aslot ^ ((arow >> 1) & 3);
    const float* aptr[3];
#pragma unroll
    for (int m = 0; m < 3; m++)
        aptr[m] = XA[m] + (size_t)(tileM + arow) * 512 + aslot * 8;

    floatx4 acc[3][2][2];
#pragma unroll
    for (int m = 0; m < 3; m++)
#pragma unroll
        for (int i = 0; i < 2; i++)
#pragma unroll
            for (int j = 0; j < 2; j++)
                acc[m][i][j] = (floatx4){0.f, 0.f, 0.f, 0.f};

    // ---- prologue: stage K-tile 0 into buffer 0
#pragma unroll
    for (int i = 0; i < 3; i++) {
        int c = wave * 3 + i, m = c >> 2, ch = c & 3;
        int r = ch * 16 + lr4, s = ls ^ ((r >> 1) & 3);
        async16(WT[m] + (size_t)(tileN + r) * 512 + s * 8,
                &smem[12288 + m * 2048 + ch * 512]);
    }
#pragma unroll
    for (int m = 0; m < 3; m++) {
        float4 a0 = *(const float4*)aptr[m];
        float4 a1 = *(const float4*)(aptr[m] + 4);
        *(short8*)&smem[m * 2048 + arow * 32 + asw * 8] = cvt8(a0, a1);
    }
    __syncthreads();

    for (int t = 0; t < 16; ++t) {
        const int cur = t & 1, nxt = cur ^ 1;
        float4 na[3][2];
        if (t < 15) {
#pragma unroll
            for (int m = 0; m < 3; m++) {
                const float* p = aptr[m] + (t + 1) * 32;
                na[m][0] = *(const float4*)p;
                na[m][1] = *(const float4*)(p + 4);
            }
#pragma unroll
            for (int i = 0; i < 3; i++) {
                int c = wave * 3 + i, m = c >> 2, ch = c & 3;
                int r = ch * 16 + lr4, s = ls ^ ((r >> 1) & 3);
                async16(WT[m] + (size_t)(tileN + r) * 512 + (t + 1) * 32 + s * 8,
                        &smem[12288 + (nxt * 3 + m) * 2048 + ch * 512]);
            }
        }
#pragma unroll
        for (int m = 0; m < 3; m++) {
            short8 afr[2], bfr[2];
#pragma unroll
            for (int mi = 0; mi < 2; ++mi) {
                int r = wm * 32 + mi * 16 + lrow;
                int s = sk ^ ((r >> 1) & 3);
                afr[mi] = *(const short8*)&smem[(cur * 3 + m) * 2048 + r * 32 + s * 8];
            }
#pragma unroll
            for (int ni = 0; ni < 2; ++ni) {
                int r = wn * 32 + ni * 16 + lrow;
                int s = sk ^ ((r >> 1) & 3);
                bfr[ni] = *(const short8*)&smem[12288 + (cur * 3 + m) * 2048 + r * 32 + s * 8];
            }
#pragma unroll
            for (int mi = 0; mi < 2; ++mi)
#pragma unroll
                for (int ni = 0; ni < 2; ++ni)
                    acc[m][mi][ni] = __builtin_amdgcn_mfma_f32_16x16x32_bf16(
                        afr[mi], bfr[ni], acc[m][mi][ni], 0, 0, 0);
        }
        if (t < 15) {
#pragma unroll
            for (int m = 0; m < 3; m++)
                *(short8*)&smem[(nxt * 3 + m) * 2048 + arow * 32 + asw * 8] =
                    cvt8(na[m][0], na[m][1]);
        }
        __syncthreads();
    }

    // ---- write overlay: q bf16; k f32 pre-scaled by 1/sqrt(64); v f32
    u16* q_ov = smem;                       // [64][68] u16
    float* k_ov = (float*)(smem + 4352);    // byte 8704, [64][68] f32
    float* v_ov = (float*)(smem + 13056);   // byte 26112, [64][68] f32
#pragma unroll
    for (int mi = 0; mi < 2; ++mi)
#pragma unroll
        for (int ni = 0; ni < 2; ++ni) {
            int col = wn * 32 + ni * 16 + lrow;
            float bq_ = bq[tileN + col];
            float bk_ = bk[tileN + col];
            float bv_ = bv[tileN + col];
#pragma unroll
            for (int r2 = 0; r2 < 4; r2++) {
                int row = wm * 32 + mi * 16 + sk * 4 + r2;
                q_ov[row * 68 + col] = f2b(acc[0][mi][ni][r2] + bq_);
                k_ov[row * 68 + col] = (acc[1][mi][ni][r2] + bk_) * 0.125f;
                v_ov[row * 68 + col] = acc[2][mi][ni][r2] + bv_;
            }
        }
    __syncthreads();

    // ---- rank-1 channel attention: lane = output channel; broadcast f32
    // float4 reads of k,v (wave-uniform addr -> conflict-free broadcast)
    for (int i = 0; i < 16; ++i) {
        int nl = wave * 16 + i;  // local row
        float qi = b2f(q_ov[nl * 68 + lane]);
        const float* krow = k_ov + nl * 68;
        const float* vrow = v_ov + nl * 68;
        float num = 0.f, den = 0.f;
#pragma unroll
        for (int j = 0; j < 64; j += 4) {
            float4 kv = *(const float4*)(krow + j);
            float4 vv = *(const float4*)(vrow + j);
            float e0 = __expf(qi * kv.x);
            float e1 = __expf(qi * kv.y);
            float e2 = __expf(qi * kv.z);
            float e3 = __expf(qi * kv.w);
            den += e0 + e1 + e2 + e3;
            num += e0 * vv.x + e1 * vv.y + e2 * vv.z + e3 * vv.w;
        }
        size_t gi = (size_t)(tileM + nl) * 512 + tileN + lane;
        Tb[gi] = f2b(xq[gi] - num / den);
    }
}

// ---------- 3. output GEMM: C = T[M,K] @ Wto[N,K]^T + bo (fp32 out) ----------
// BM=64, BN=64, 512 blocks (2/CU), 2-phase double buffer.
__global__ __launch_bounds__(256, 2) void out_gemm(const u16* __restrict__ T,
                                                   const u16* __restrict__ wto,
                                                   const float* __restrict__ bo,
                                                   float* __restrict__ C) {
    __shared__ __align__(16) u16 sA[2][2048];
    __shared__ __align__(16) u16 sB[2][2048];
    const int d = blockIdx.x;
    const int id = (d & 7) * 64 + (d >> 3);
    const int tileM = (id >> 3) * 64;
    const int tileN = (id & 7) * 64;

    const int tid = threadIdx.x;
    const int wave = tid >> 6, lane = tid & 63;
    const int wm = wave >> 1, wn = wave & 1;
    const int lr4 = lane >> 2, ls = lane & 3;
    const int lrow = lane & 15, sk = lane >> 4;

    const int r0 = wave * 16 + lr4;
    const int s0 = ls ^ ((r0 >> 1) & 3);
    const u16* aptr = T + (size_t)(tileM + r0) * 512 + s0 * 8;
    const u16* bptr = wto + (size_t)(tileN + r0) * 512 + s0 * 8;

    floatx4 acc[2][2];
#pragma unroll
    for (int i = 0; i < 2; i++)
#pragma unroll
        for (int j = 0; j < 2; j++) acc[i][j] = (floatx4){0.f, 0.f, 0.f, 0.f};

    async16(aptr, &sA[0][wave * 512]);
    async16(bptr, &sB[0][wave * 512]);
    __syncthreads();

    for (int t = 0; t < 16; ++t) {
        const int cur = t & 1, nxt = cur ^ 1;
        if (t < 15) {
            async16(aptr + (t + 1) * 32, &sA[nxt][wave * 512]);
            async16(bptr + (t + 1) * 32, &sB[nxt][wave * 512]);
        }
        short8 afr[2], bfr[2];
#pragma unroll
        for (int mi = 0; mi < 2; ++mi) {
            int r = wm * 32 + mi * 16 + lrow;
            int s = sk ^ ((r >> 1) & 3);
            afr[mi] = *(const short8*)&sA[cur][r * 32 + s * 8];
        }
#pragma unroll
        for (int ni = 0; ni < 2; ++ni) {
            int r = wn * 32 + ni * 16 + lrow;
            int s = sk ^ ((r >> 1) & 3);
            bfr[ni] = *(const short8*)&sB[cur][r * 32 + s * 8];
        }
#pragma unroll
        for (int mi = 0; mi < 2; ++mi)
#pragma unroll
            for (int ni = 0; ni < 2; ++ni)
                acc[mi][ni] = __builtin_amdgcn_mfma_f32_16x16x32_bf16(
                    afr[mi], bfr[ni], acc[mi][ni], 0, 0, 0);
        __syncthreads();
    }

#pragma unroll
    for (int mi = 0; mi < 2; ++mi)
#pragma unroll
        for (int ni = 0; ni < 2; ++ni) {
            int col = tileN + wn * 32 + ni * 16 + lrow;
            float bv = bo[col];
#pragma unroll
            for (int r2 = 0; r2 < 4; r2++) {
                int row = tileM + wm * 32 + mi * 16 + sk * 4 + r2;
                C[(size_t)row * 512 + col] = acc[mi][ni][r2] + bv;
            }
        }
}

// ---------- launch ----------
extern "C" void kernel_launch(void* const* d_in, const int* in_sizes, int n_in,
                              void* d_out, int out_size, void* d_ws,
                              size_t ws_size, hipStream_t stream) {
    const float* x_q = (const float*)d_in[0];
    const float* x_k = (const float*)d_in[1];
    const float* x_v = (const float*)d_in[2];
    const float* Wq = (const float*)d_in[3];
    const float* bq = (const float*)d_in[4];
    const float* Wk = (const float*)d_in[5];
    const float* bk = (const float*)d_in[6];
    const float* Wv = (const float*)d_in[7];
    const float* bv = (const float*)d_in[8];
    const float* Wo = (const float*)d_in[9];
    const float* bo = (const float*)d_in[10];

    u16* ws = (u16*)d_ws;
    u16* wtq = ws;
    u16* wtk = wtq + DD;
    u16* wtv = wtk + DD;
    u16* wto = wtv + DD;
    u16* Tb = wto + DD;

    convert_w<<<dim3(16, 16, 4), dim3(32, 8), 0, stream>>>(Wq, Wk, Wv, Wo, wtq,
                                                           wtk, wtv, wto);
    proj_attn<<<dim3(512), 256, 0, stream>>>(x_q, x_k, x_v, wtq, wtk, wtv, bq,
                                             bk, bv, Tb);
    out_gemm<<<dim3(512), 256, 0, stream>>>(Tb, wto, bo, (float*)d_out);
}

// Round 6
// 138.492 us; speedup vs baseline: 1.1049x; 1.0570x over previous
//
#include <hip/hip_runtime.h>
#include <hip/hip_bf16.h>

#define NROWS 4096
#define DMODEL 512
#define NHEAD 8
#define DKH 64
#define ND (NROWS * DMODEL)   // 2097152
#define DD (DMODEL * DMODEL)  // 262144

typedef unsigned short u16;
typedef __attribute__((ext_vector_type(8))) short short8;
typedef __attribute__((ext_vector_type(4))) float floatx4;

// ---------- helpers ----------
__device__ __forceinline__ u16 f2b(float f) {
    unsigned u = __float_as_uint(f);
    unsigned r = (u + 0x7fffu + ((u >> 16) & 1u)) >> 16;
    return (u16)r;
}
__device__ __forceinline__ float b2f(u16 v) {
    return __uint_as_float(((unsigned)v) << 16);
}
__device__ __forceinline__ void async16(const void* g, void* l) {
    // global -> LDS direct, 16B/lane; LDS dest = wave-uniform base + lane*16
    __builtin_amdgcn_global_load_lds(g, l, 16, 0, 0);
}
__device__ __forceinline__ short8 cvt8(float4 a0, float4 a1) {
    short8 av;
    av[0] = f2b(a0.x); av[1] = f2b(a0.y); av[2] = f2b(a0.z); av[3] = f2b(a0.w);
    av[4] = f2b(a1.x); av[5] = f2b(a1.y); av[6] = f2b(a1.z); av[7] = f2b(a1.w);
    return av;
}

// ---------- 1. prep: W(KxN)->Wt(NxK) bf16 (blocks 0..1023) +
//                     x fp32->bf16 (blocks 1024..4095, 2048 elems/block) ----
__global__ __launch_bounds__(256) void prep(
    const float* __restrict__ W0, const float* __restrict__ W1,
    const float* __restrict__ W2, const float* __restrict__ W3,
    u16* __restrict__ T0, u16* __restrict__ T1, u16* __restrict__ T2,
    u16* __restrict__ T3, const float* __restrict__ x0,
    const float* __restrict__ x1, const float* __restrict__ x2,
    u16* __restrict__ y0, u16* __restrict__ y1, u16* __restrict__ y2) {
    const int bid = blockIdx.x;
    const int tid = threadIdx.x;
    if (bid < 1024) {
        __shared__ float tile[32][33];
        int z = bid >> 8, t = bid & 255;
        const float* W = z == 0 ? W0 : (z == 1 ? W1 : (z == 2 ? W2 : W3));
        u16* T = z == 0 ? T0 : (z == 1 ? T1 : (z == 2 ? T2 : T3));
        int n0 = (t & 15) * 32, k0 = (t >> 4) * 32;
        int tx = tid & 31, ty = tid >> 5;  // 32 x 8
#pragma unroll
        for (int r = 0; r < 32; r += 8)
            tile[ty + r][tx] = W[(size_t)(k0 + ty + r) * DMODEL + n0 + tx];
        __syncthreads();
#pragma unroll
        for (int r = 0; r < 32; r += 8)
            T[(size_t)(n0 + ty + r) * DMODEL + k0 + tx] = f2b(tile[tx][ty + r]);
    } else {
        int b = bid - 1024;           // 0..3071, 1024 blocks per array
        int zz = b >> 10;
        const float* s = zz == 0 ? x0 : (zz == 1 ? x1 : x2);
        u16* d = zz == 0 ? y0 : (zz == 1 ? y1 : y2);
        int i = (b & 1023) * 2048 + tid * 8;
        float4 a0 = *(const float4*)(s + i);
        float4 a1 = *(const float4*)(s + i + 4);
        *(short8*)(d + i) = cvt8(a0, a1);
    }
}

// ---------- 2. projection GEMM (pure async16, m97-style staging) ----------
// C[4096,512] = A_bf16[M,K] @ Wt[N,K]^T + bias, per z in {Q,K,V}.
// BM=64, BN=128, BK=32. 4 waves (2x2), per-wave 32x64, acc[2][4].
// Double-buffered, 1 barrier/K-step. 768 blocks = 3/CU (12 waves/CU).
__global__ __launch_bounds__(256, 3) void proj3(
    const u16* __restrict__ xqb, const u16* __restrict__ xkb,
    const u16* __restrict__ xvb, const u16* __restrict__ wtq,
    const u16* __restrict__ wtk, const u16* __restrict__ wtv,
    const float* __restrict__ bq, const float* __restrict__ bk,
    const float* __restrict__ bv, u16* __restrict__ Q, u16* __restrict__ K,
    u16* __restrict__ V) {
    __shared__ __align__(16) u16 sA[2][64 * 32];    // 8 KB
    __shared__ __align__(16) u16 sB[2][128 * 32];   // 16 KB

    const int d = blockIdx.x;
    const int id = (d & 7) * 96 + (d >> 3);  // XCD-chunked
    const int z = id >> 8;
    const int t2 = id & 255;
    const int tileM = (t2 >> 2) * 64;
    const int tileN = (t2 & 3) * 128;

    const u16* A = z == 0 ? xqb : (z == 1 ? xkb : xvb);
    const u16* Bt = z == 0 ? wtq : (z == 1 ? wtk : wtv);
    const float* bias = z == 0 ? bq : (z == 1 ? bk : bv);
    u16* C = z == 0 ? Q : (z == 1 ? K : V);

    const int tid = threadIdx.x;
    const int wave = tid >> 6, lane = tid & 63;
    const int wm = wave >> 1, wn = wave & 1;
    const int lr4 = lane >> 2, ls = lane & 3;
    const int lrow = lane & 15, sk = lane >> 4;

    // A: 4 chunks of 16 rows, 1 per wave
    const int ra = wave * 16 + lr4;
    const int sa = ls ^ ((ra >> 1) & 3);
    const u16* aptr = A + (size_t)(tileM + ra) * 512 + sa * 8;
    // B: 8 chunks, 2 per wave
    const int rb0 = (wave * 2) * 16 + lr4;
    const int rb1 = (wave * 2 + 1) * 16 + lr4;
    const int sb0 = ls ^ ((rb0 >> 1) & 3);
    const int sb1 = ls ^ ((rb1 >> 1) & 3);
    const u16* bptr0 = Bt + (size_t)(tileN + rb0) * 512 + sb0 * 8;
    const u16* bptr1 = Bt + (size_t)(tileN + rb1) * 512 + sb1 * 8;

    floatx4 acc[2][4];
#pragma unroll
    for (int i = 0; i < 2; i++)
#pragma unroll
        for (int j = 0; j < 4; j++) acc[i][j] = (floatx4){0.f, 0.f, 0.f, 0.f};

    async16(aptr, &sA[0][wave * 512]);
    async16(bptr0, &sB[0][wave * 1024]);
    async16(bptr1, &sB[0][wave * 1024 + 512]);
    __syncthreads();

    for (int t = 0; t < 16; ++t) {
        const int cur = t & 1, nxt = cur ^ 1;
        if (t < 15) {
            async16(aptr + (t + 1) * 32, &sA[nxt][wave * 512]);
            async16(bptr0 + (t + 1) * 32, &sB[nxt][wave * 1024]);
            async16(bptr1 + (t + 1) * 32, &sB[nxt][wave * 1024 + 512]);
        }
        short8 afr[2], bfr[4];
#pragma unroll
        for (int mi = 0; mi < 2; ++mi) {
            int r = wm * 32 + mi * 16 + lrow;
            int s = sk ^ ((r >> 1) & 3);
            afr[mi] = *(const short8*)&sA[cur][r * 32 + s * 8];
        }
#pragma unroll
        for (int ni = 0; ni < 4; ++ni) {
            int r = wn * 64 + ni * 16 + lrow;
            int s = sk ^ ((r >> 1) & 3);
            bfr[ni] = *(const short8*)&sB[cur][r * 32 + s * 8];
        }
#pragma unroll
        for (int mi = 0; mi < 2; ++mi)
#pragma unroll
            for (int ni = 0; ni < 4; ++ni)
                acc[mi][ni] = __builtin_amdgcn_mfma_f32_16x16x32_bf16(
                    afr[mi], bfr[ni], acc[mi][ni], 0, 0, 0);
        __syncthreads();
    }

    // epilogue: C/D layout col = lane&15, row = (lane>>4)*4 + reg
#pragma unroll
    for (int mi = 0; mi < 2; ++mi)
#pragma unroll
        for (int ni = 0; ni < 4; ++ni) {
            int col = tileN + wn * 64 + ni * 16 + lrow;
            float bv_ = bias[col];
#pragma unroll
            for (int r2 = 0; r2 < 4; r2++) {
                int row = tileM + wm * 32 + mi * 16 + sk * 4 + r2;
                C[(size_t)row * 512 + col] = f2b(acc[mi][ni][r2] + bv_);
            }
        }
}

// ---------- 3. rank-1 channel attention + residual-diff ----------
// per (n,h): att[i] = sum_j exp(q_i*k_j/8) v_j / sum_j exp(q_i*k_j/8)
// 8192 blocks x 4 waves: massive TLP hides all latencies.
__global__ __launch_bounds__(256) void attn_kernel(
    const u16* __restrict__ Qb, const u16* __restrict__ Kb,
    const u16* __restrict__ Vb, const float* __restrict__ xq,
    u16* __restrict__ Tout) {
    __shared__ float lk[4][64];
    __shared__ float lv[4][64];
    const int wave = threadIdx.x >> 6, lane = threadIdx.x & 63;
    const int p = blockIdx.x * 4 + wave;  // (n,h) pair, < 32768
    const int n = p >> 3, h = p & 7;
    const size_t base = (size_t)n * DMODEL + h * DKH;

    float qi = b2f(Qb[base + lane]) * 0.125f;  // fold 1/sqrt(64) into q
    lk[wave][lane] = b2f(Kb[base + lane]);
    lv[wave][lane] = b2f(Vb[base + lane]);
    __syncthreads();

    float num = 0.f, den = 0.f;
#pragma unroll
    for (int j = 0; j < 64; j += 4) {
        float4 kv = *(const float4*)&lk[wave][j];
        float4 vv = *(const float4*)&lv[wave][j];
        float e0 = __expf(qi * kv.x);
        float e1 = __expf(qi * kv.y);
        float e2 = __expf(qi * kv.z);
        float e3 = __expf(qi * kv.w);
        den += e0 + e1 + e2 + e3;
        num += e0 * vv.x + e1 * vv.y + e2 * vv.z + e3 * vv.w;
    }
    float t = xq[base + lane] - num / den;
    Tout[base + lane] = f2b(t);
}

// ---------- 4. output GEMM: C = T[M,K] @ Wto[N,K]^T + bo (fp32 out) ----------
// BM=64, BN=64, 512 blocks (2/CU), 2-phase double buffer.
__global__ __launch_bounds__(256, 2) void out_gemm(const u16* __restrict__ T,
                                                   const u16* __restrict__ wto,
                                                   const float* __restrict__ bo,
                                                   float* __restrict__ C) {
    __shared__ __align__(16) u16 sA[2][2048];
    __shared__ __align__(16) u16 sB[2][2048];
    const int d = blockIdx.x;
    const int id = (d & 7) * 64 + (d >> 3);
    const int tileM = (id >> 3) * 64;
    const int tileN = (id & 7) * 64;

    const int tid = threadIdx.x;
    const int wave = tid >> 6, lane = tid & 63;
    const int wm = wave >> 1, wn = wave & 1;
    const int lr4 = lane >> 2, ls = lane & 3;
    const int lrow = lane & 15, sk = lane >> 4;

    const int r0 = wave * 16 + lr4;
    const int s0 = ls ^ ((r0 >> 1) & 3);
    const u16* aptr = T + (size_t)(tileM + r0) * 512 + s0 * 8;
    const u16* bptr = wto + (size_t)(tileN + r0) * 512 + s0 * 8;

    floatx4 acc[2][2];
#pragma unroll
    for (int i = 0; i < 2; i++)
#pragma unroll
        for (int j = 0; j < 2; j++) acc[i][j] = (floatx4){0.f, 0.f, 0.f, 0.f};

    async16(aptr, &sA[0][wave * 512]);
    async16(bptr, &sB[0][wave * 512]);
    __syncthreads();

    for (int t = 0; t < 16; ++t) {
        const int cur = t & 1, nxt = cur ^ 1;
        if (t < 15) {
            async16(aptr + (t + 1) * 32, &sA[nxt][wave * 512]);
            async16(bptr + (t + 1) * 32, &sB[nxt][wave * 512]);
        }
        short8 afr[2], bfr[2];
#pragma unroll
        for (int mi = 0; mi < 2; ++mi) {
            int r = wm * 32 + mi * 16 + lrow;
            int s = sk ^ ((r >> 1) & 3);
            afr[mi] = *(const short8*)&sA[cur][r * 32 + s * 8];
        }
#pragma unroll
        for (int ni = 0; ni < 2; ++ni) {
            int r = wn * 32 + ni * 16 + lrow;
            int s = sk ^ ((r >> 1) & 3);
            bfr[ni] = *(const short8*)&sB[cur][r * 32 + s * 8];
        }
#pragma unroll
        for (int mi = 0; mi < 2; ++mi)
#pragma unroll
            for (int ni = 0; ni < 2; ++ni)
                acc[mi][ni] = __builtin_amdgcn_mfma_f32_16x16x32_bf16(
                    afr[mi], bfr[ni], acc[mi][ni], 0, 0, 0);
        __syncthreads();
    }

#pragma unroll
    for (int mi = 0; mi < 2; ++mi)
#pragma unroll
        for (int ni = 0; ni < 2; ++ni) {
            int col = tileN + wn * 32 + ni * 16 + lrow;
            float bv = bo[col];
#pragma unroll
            for (int r2 = 0; r2 < 4; r2++) {
                int row = tileM + wm * 32 + mi * 16 + sk * 4 + r2;
                C[(size_t)row * 512 + col] = acc[mi][ni][r2] + bv;
            }
        }
}

// ---------- launch ----------
extern "C" void kernel_launch(void* const* d_in, const int* in_sizes, int n_in,
                              void* d_out, int out_size, void* d_ws,
                              size_t ws_size, hipStream_t stream) {
    const float* x_q = (const float*)d_in[0];
    const float* x_k = (const float*)d_in[1];
    const float* x_v = (const float*)d_in[2];
    const float* Wq = (const float*)d_in[3];
    const float* bq = (const float*)d_in[4];
    const float* Wk = (const float*)d_in[5];
    const float* bk = (const float*)d_in[6];
    const float* Wv = (const float*)d_in[7];
    const float* bv = (const float*)d_in[8];
    const float* Wo = (const float*)d_in[9];
    const float* bo = (const float*)d_in[10];

    u16* ws = (u16*)d_ws;
    u16* xqb = ws;
    u16* xkb = xqb + ND;
    u16* xvb = xkb + ND;
    u16* wtq = xvb + ND;
    u16* wtk = wtq + DD;
    u16* wtv = wtk + DD;
    u16* wto = wtv + DD;
    u16* Qb = wto + DD;
    u16* Kb = Qb + ND;
    u16* Vb = Kb + ND;
    u16* Tb = Vb + ND;

    prep<<<dim3(4096), 256, 0, stream>>>(Wq, Wk, Wv, Wo, wtq, wtk, wtv, wto,
                                         x_q, x_k, x_v, xqb, xkb, xvb);
    proj3<<<dim3(768), 256, 0, stream>>>(xqb, xkb, xvb, wtq, wtk, wtv, bq, bk,
                                         bv, Qb, Kb, Vb);
    attn_kernel<<<dim3(NROWS * NHEAD / 4), 256, 0, stream>>>(Qb, Kb, Vb, x_q,
                                                             Tb);
    out_gemm<<<dim3(512), 256, 0, stream>>>(Tb, wto, bo, (float*)d_out);
}

// Round 7
// 134.025 us; speedup vs baseline: 1.1418x; 1.0333x over previous
//
#include <hip/hip_runtime.h>
#include <hip/hip_bf16.h>

#define NROWS 4096
#define DMODEL 512
#define NHEAD 8
#define DKH 64
#define ND (NROWS * DMODEL)   // 2097152
#define DD (DMODEL * DMODEL)  // 262144

typedef unsigned short u16;
typedef __attribute__((ext_vector_type(8))) short short8;
typedef __attribute__((ext_vector_type(4))) float floatx4;

// ---------- helpers ----------
__device__ __forceinline__ u16 f2b(float f) {
    unsigned u = __float_as_uint(f);
    unsigned r = (u + 0x7fffu + ((u >> 16) & 1u)) >> 16;
    return (u16)r;
}
__device__ __forceinline__ float b2f(u16 v) {
    return __uint_as_float(((unsigned)v) << 16);
}
__device__ __forceinline__ void async16(const void* g, void* l) {
    // global -> LDS direct, 16B/lane; LDS dest = wave-uniform base + lane*16
    __builtin_amdgcn_global_load_lds(g, l, 16, 0, 0);
}
__device__ __forceinline__ short8 cvt8(float4 a0, float4 a1) {
    short8 av;
    av[0] = f2b(a0.x); av[1] = f2b(a0.y); av[2] = f2b(a0.z); av[3] = f2b(a0.w);
    av[4] = f2b(a1.x); av[5] = f2b(a1.y); av[6] = f2b(a1.z); av[7] = f2b(a1.w);
    return av;
}

// ---------- 1. prep_w: W (KxN) fp32 -> Wt (NxK) bf16, 1024 blocks ----------
__global__ __launch_bounds__(256) void prep_w(
    const float* __restrict__ W0, const float* __restrict__ W1,
    const float* __restrict__ W2, const float* __restrict__ W3,
    u16* __restrict__ T0, u16* __restrict__ T1, u16* __restrict__ T2,
    u16* __restrict__ T3) {
    __shared__ float tile[32][33];
    const int z = blockIdx.x >> 8, t = blockIdx.x & 255;
    const float* W = z == 0 ? W0 : (z == 1 ? W1 : (z == 2 ? W2 : W3));
    u16* T = z == 0 ? T0 : (z == 1 ? T1 : (z == 2 ? T2 : T3));
    int n0 = (t & 15) * 32, k0 = (t >> 4) * 32;
    int tx = threadIdx.x & 31, ty = threadIdx.x >> 5;  // 32 x 8
#pragma unroll
    for (int r = 0; r < 32; r += 8)
        tile[ty + r][tx] = W[(size_t)(k0 + ty + r) * DMODEL + n0 + tx];
    __syncthreads();
#pragma unroll
    for (int r = 0; r < 32; r += 8)
        T[(size_t)(n0 + ty + r) * DMODEL + k0 + tx] = f2b(tile[tx][ty + r]);
}

// ---------- 2. projection GEMM, BK=64, fused fp32->bf16 A staging ----------
// C[4096,512] = bf16(x)[M,K] @ Wt[N,K]^T + bias, per z in {Q,K,V}.
// BM=64, BN=128, BK=64. 4 waves (2x2), per-wave 32x64, acc[2][4].
// Double-buffered, 1 barrier per BK=64 step (8 barriers total).
// LDS 48KB -> 3 blocks/CU.  16 MFMA / wave / barrier.
__global__ __launch_bounds__(256, 3) void proj3(
    const float* __restrict__ xq, const float* __restrict__ xk,
    const float* __restrict__ xv, const u16* __restrict__ wtq,
    const u16* __restrict__ wtk, const u16* __restrict__ wtv,
    const float* __restrict__ bq, const float* __restrict__ bk,
    const float* __restrict__ bv, u16* __restrict__ Q, u16* __restrict__ K,
    u16* __restrict__ V) {
    __shared__ __align__(16) u16 sA[2][64 * 64];    // 16 KB
    __shared__ __align__(16) u16 sB[2][128 * 64];   // 32 KB

    const int d = blockIdx.x;
    const int id = (d & 7) * 96 + (d >> 3);  // XCD-chunked (768 = 8*96)
    const int z = id >> 8;
    const int t2 = id & 255;
    const int tileM = (t2 >> 2) * 64;
    const int tileN = (t2 & 3) * 128;  // 4 N-tiles of one M-panel adjacent

    const float* A = z == 0 ? xq : (z == 1 ? xk : xv);
    const u16* Bt = z == 0 ? wtq : (z == 1 ? wtk : wtv);
    const float* bias = z == 0 ? bq : (z == 1 ? bk : bv);
    u16* C = z == 0 ? Q : (z == 1 ? K : V);

    const int tid = threadIdx.x;
    const int wave = tid >> 6, lane = tid & 63;
    const int wm = wave >> 1, wn = wave & 1;
    const int lrow = lane & 15, sk = lane >> 4;

    // A reg-staging: row = tid>>2 (4 thr/row), thread covers 16 f32 = 2 slots
    const int arow = tid >> 2, apair = tid & 3;
    const int axor = (arow >> 1) & 7;
    const int as0 = (2 * apair) ^ axor;      // swizzled 8-elem slot
    const int as1 = (2 * apair + 1) ^ axor;
    const float* aptr = A + (size_t)(tileM + arow) * 512 + apair * 16;
    const int aw0 = arow * 64 + as0 * 8;     // u16 offset within buffer
    const int aw1 = arow * 64 + as1 * 8;

    // B async16 staging: 16 chunks of 8 rows (1KB), 4 per wave.
    // lane -> row = c*8 + (lane>>3); global src slot pre-swizzled.
    const u16* bptr[4];
    int bdst[4];
#pragma unroll
    for (int i = 0; i < 4; i++) {
        int c = wave * 4 + i;
        int row = c * 8 + (lane >> 3);
        int s = (lane & 7) ^ ((row >> 1) & 7);
        bptr[i] = Bt + (size_t)(tileN + row) * 512 + s * 8;
        bdst[i] = c * 512;
    }

    floatx4 acc[2][4];
#pragma unroll
    for (int i = 0; i < 2; i++)
#pragma unroll
        for (int j = 0; j < 4; j++) acc[i][j] = (floatx4){0.f, 0.f, 0.f, 0.f};

    // ---- prologue: stage K-step 0 into buffer 0
#pragma unroll
    for (int i = 0; i < 4; i++) async16(bptr[i], &sB[0][bdst[i]]);
    {
        float4 a0 = *(const float4*)aptr;
        float4 a1 = *(const float4*)(aptr + 4);
        float4 a2 = *(const float4*)(aptr + 8);
        float4 a3 = *(const float4*)(aptr + 12);
        *(short8*)&sA[0][aw0] = cvt8(a0, a1);
        *(short8*)&sA[0][aw1] = cvt8(a2, a3);
    }
    __syncthreads();

    for (int t = 0; t < 8; ++t) {
        const int cur = t & 1, nxt = cur ^ 1;
        float4 n0, n1, n2, n3;
        if (t < 7) {
            const float* p = aptr + (t + 1) * 64;
            n0 = *(const float4*)p;
            n1 = *(const float4*)(p + 4);
            n2 = *(const float4*)(p + 8);
            n3 = *(const float4*)(p + 12);
#pragma unroll
            for (int i = 0; i < 4; i++)
                async16(bptr[i] + (t + 1) * 64, &sB[nxt][bdst[i]]);
        }
        // frags: kk = which 32-wide K half of the 64-wide step
        short8 afr[2][2], bfr[2][4];
#pragma unroll
        for (int kk = 0; kk < 2; ++kk) {
#pragma unroll
            for (int mi = 0; mi < 2; ++mi) {
                int r = wm * 32 + mi * 16 + lrow;
                int s = (kk * 4 + sk) ^ ((r >> 1) & 7);
                afr[kk][mi] = *(const short8*)&sA[cur][r * 64 + s * 8];
            }
#pragma unroll
            for (int ni = 0; ni < 4; ++ni) {
                int r = wn * 64 + ni * 16 + lrow;
                int s = (kk * 4 + sk) ^ ((r >> 1) & 7);
                bfr[kk][ni] = *(const short8*)&sB[cur][r * 64 + s * 8];
            }
        }
#pragma unroll
        for (int kk = 0; kk < 2; ++kk)
#pragma unroll
            for (int mi = 0; mi < 2; ++mi)
#pragma unroll
                for (int ni = 0; ni < 4; ++ni)
                    acc[mi][ni] = __builtin_amdgcn_mfma_f32_16x16x32_bf16(
                        afr[kk][mi], bfr[kk][ni], acc[mi][ni], 0, 0, 0);
        if (t < 7) {
            *(short8*)&sA[nxt][aw0] = cvt8(n0, n1);
            *(short8*)&sA[nxt][aw1] = cvt8(n2, n3);
        }
        __syncthreads();
    }

    // epilogue: C/D layout col = lane&15, row = (lane>>4)*4 + reg
#pragma unroll
    for (int mi = 0; mi < 2; ++mi)
#pragma unroll
        for (int ni = 0; ni < 4; ++ni) {
            int col = tileN + wn * 64 + ni * 16 + lrow;
            float bv_ = bias[col];
#pragma unroll
            for (int r2 = 0; r2 < 4; r2++) {
                int row = tileM + wm * 32 + mi * 16 + sk * 4 + r2;
                C[(size_t)row * 512 + col] = f2b(acc[mi][ni][r2] + bv_);
            }
        }
}

// ---------- 3. rank-1 channel attention + residual-diff ----------
// per (n,h): att[i] = sum_j exp(q_i*k_j/8) v_j / sum_j exp(q_i*k_j/8)
__global__ __launch_bounds__(256) void attn_kernel(
    const u16* __restrict__ Qb, const u16* __restrict__ Kb,
    const u16* __restrict__ Vb, const float* __restrict__ xq,
    u16* __restrict__ Tout) {
    __shared__ float lk[4][64];
    __shared__ float lv[4][64];
    const int wave = threadIdx.x >> 6, lane = threadIdx.x & 63;
    const int p = blockIdx.x * 4 + wave;  // (n,h) pair, < 32768
    const int n = p >> 3, h = p & 7;
    const size_t base = (size_t)n * DMODEL + h * DKH;

    float qi = b2f(Qb[base + lane]) * 0.125f;  // fold 1/sqrt(64) into q
    lk[wave][lane] = b2f(Kb[base + lane]);
    lv[wave][lane] = b2f(Vb[base + lane]);
    __syncthreads();

    float num = 0.f, den = 0.f;
#pragma unroll
    for (int j = 0; j < 64; j += 4) {
        float4 kv = *(const float4*)&lk[wave][j];
        float4 vv = *(const float4*)&lv[wave][j];
        float e0 = __expf(qi * kv.x);
        float e1 = __expf(qi * kv.y);
        float e2 = __expf(qi * kv.z);
        float e3 = __expf(qi * kv.w);
        den += e0 + e1 + e2 + e3;
        num += e0 * vv.x + e1 * vv.y + e2 * vv.z + e3 * vv.w;
    }
    float t = xq[base + lane] - num / den;
    Tout[base + lane] = f2b(t);
}

// ---------- 4. output GEMM: C = T[M,K] @ Wto[N,K]^T + bo, BK=64 ----------
// BM=64, BN=64, 512 blocks (2/CU), double-buffered, 8 barriers.
__global__ __launch_bounds__(256, 2) void out_gemm(const u16* __restrict__ T,
                                                   const u16* __restrict__ wto,
                                                   const float* __restrict__ bo,
                                                   float* __restrict__ C) {
    __shared__ __align__(16) u16 sA[2][64 * 64];
    __shared__ __align__(16) u16 sB[2][64 * 64];
    const int d = blockIdx.x;
    const int id = (d & 7) * 64 + (d >> 3);
    const int tileM = (id >> 3) * 64;
    const int tileN = (id & 7) * 64;

    const int tid = threadIdx.x;
    const int wave = tid >> 6, lane = tid & 63;
    const int wm = wave >> 1, wn = wave & 1;
    const int lrow = lane & 15, sk = lane >> 4;

    // staging: 8 chunks of 8 rows per matrix, 2 per wave each
    const u16* aptr[2];
    const u16* bptr[2];
    int dst[2];
#pragma unroll
    for (int i = 0; i < 2; i++) {
        int c = wave * 2 + i;
        int row = c * 8 + (lane >> 3);
        int s = (lane & 7) ^ ((row >> 1) & 7);
        aptr[i] = T + (size_t)(tileM + row) * 512 + s * 8;
        bptr[i] = wto + (size_t)(tileN + row) * 512 + s * 8;
        dst[i] = c * 512;
    }

    floatx4 acc[2][2];
#pragma unroll
    for (int i = 0; i < 2; i++)
#pragma unroll
        for (int j = 0; j < 2; j++) acc[i][j] = (floatx4){0.f, 0.f, 0.f, 0.f};

#pragma unroll
    for (int i = 0; i < 2; i++) {
        async16(aptr[i], &sA[0][dst[i]]);
        async16(bptr[i], &sB[0][dst[i]]);
    }
    __syncthreads();

    for (int t = 0; t < 8; ++t) {
        const int cur = t & 1, nxt = cur ^ 1;
        if (t < 7) {
#pragma unroll
            for (int i = 0; i < 2; i++) {
                async16(aptr[i] + (t + 1) * 64, &sA[nxt][dst[i]]);
                async16(bptr[i] + (t + 1) * 64, &sB[nxt][dst[i]]);
            }
        }
        short8 afr[2][2], bfr[2][2];
#pragma unroll
        for (int kk = 0; kk < 2; ++kk) {
#pragma unroll
            for (int mi = 0; mi < 2; ++mi) {
                int r = wm * 32 + mi * 16 + lrow;
                int s = (kk * 4 + sk) ^ ((r >> 1) & 7);
                afr[kk][mi] = *(const short8*)&sA[cur][r * 64 + s * 8];
            }
#pragma unroll
            for (int ni = 0; ni < 2; ++ni) {
                int r = wn * 32 + ni * 16 + lrow;
                int s = (kk * 4 + sk) ^ ((r >> 1) & 7);
                bfr[kk][ni] = *(const short8*)&sB[cur][r * 64 + s * 8];
            }
        }
#pragma unroll
        for (int kk = 0; kk < 2; ++kk)
#pragma unroll
            for (int mi = 0; mi < 2; ++mi)
#pragma unroll
                for (int ni = 0; ni < 2; ++ni)
                    acc[mi][ni] = __builtin_amdgcn_mfma_f32_16x16x32_bf16(
                        afr[kk][mi], bfr[kk][ni], acc[mi][ni], 0, 0, 0);
        __syncthreads();
    }

#pragma unroll
    for (int mi = 0; mi < 2; ++mi)
#pragma unroll
        for (int ni = 0; ni < 2; ++ni) {
            int col = tileN + wn * 32 + ni * 16 + lrow;
            float bv = bo[col];
#pragma unroll
            for (int r2 = 0; r2 < 4; r2++) {
                int row = tileM + wm * 32 + mi * 16 + sk * 4 + r2;
                C[(size_t)row * 512 + col] = acc[mi][ni][r2] + bv;
            }
        }
}

// ---------- launch ----------
extern "C" void kernel_launch(void* const* d_in, const int* in_sizes, int n_in,
                              void* d_out, int out_size, void* d_ws,
                              size_t ws_size, hipStream_t stream) {
    const float* x_q = (const float*)d_in[0];
    const float* x_k = (const float*)d_in[1];
    const float* x_v = (const float*)d_in[2];
    const float* Wq = (const float*)d_in[3];
    const float* bq = (const float*)d_in[4];
    const float* Wk = (const float*)d_in[5];
    const float* bk = (const float*)d_in[6];
    const float* Wv = (const float*)d_in[7];
    const float* bv = (const float*)d_in[8];
    const float* Wo = (const float*)d_in[9];
    const float* bo = (const float*)d_in[10];

    u16* ws = (u16*)d_ws;
    u16* wtq = ws;
    u16* wtk = wtq + DD;
    u16* wtv = wtk + DD;
    u16* wto = wtv + DD;
    u16* Qb = wto + DD;
    u16* Kb = Qb + ND;
    u16* Vb = Kb + ND;
    u16* Tb = Vb + ND;

    prep_w<<<dim3(1024), 256, 0, stream>>>(Wq, Wk, Wv, Wo, wtq, wtk, wtv, wto);
    proj3<<<dim3(768), 256, 0, stream>>>(x_q, x_k, x_v, wtq, wtk, wtv, bq, bk,
                                         bv, Qb, Kb, Vb);
    attn_kernel<<<dim3(NROWS * NHEAD / 4), 256, 0, stream>>>(Qb, Kb, Vb, x_q,
                                                             Tb);
    out_gemm<<<dim3(512), 256, 0, stream>>>(Tb, wto, bo, (float*)d_out);
}